// Round 9
// baseline (123.006 us; speedup 1.0000x reference)
//
#include <hip/hip_runtime.h>
#include <hip/hip_bf16.h>

#define N_NODES 10000
#define E_EDGES 320000
#define D 256
#define LRELU_ALPHA 0.2f

// fp32 world (round 3). dur_us includes ~56 us of harness re-poison fills
// (round-6 forensics). GEMM via mfma_f32_16x16x32_bf16 (round-8 win).
// aggregate: column-halved so the gather table (2.56 MB) fits per-XCD L2.

using short8  = __attribute__((ext_vector_type(8))) short;
using floatx4 = __attribute__((ext_vector_type(4))) float;
using bf16 = __hip_bfloat16;

__device__ __forceinline__ float bu2f(unsigned short u) {
    return __uint_as_float((unsigned)u << 16);
}
__device__ __forceinline__ unsigned short f2bu(float f) {
    union { bf16 b; unsigned short u; } cv;
    cv.b = __float2bfloat16(f);
    return cv.u;
}

// ---------------------------------------------------------------------------
// K1: raw edges -> dst[] and CSR row_start[] in one pass. src is sorted.
// ---------------------------------------------------------------------------
__global__ __launch_bounds__(256) void prep(const int* __restrict__ raw,
                                            int* __restrict__ dst,
                                            int* __restrict__ row_start) {
    bool is64 = true;  // int64 rows: [s_lo, s_hi, d_lo, d_hi], hi words == 0
    #pragma unroll
    for (int t = 0; t < 16; ++t)
        if (raw[2 * t + 1] != 0) is64 = false;

    int e = blockIdx.x * 256 + threadIdx.x;
    if (e >= E_EDGES) return;
    int s, d, sprev;
    if (is64) { s = raw[4 * e]; d = raw[4 * e + 2]; sprev = e ? raw[4 * e - 4] : -1; }
    else      { s = raw[2 * e]; d = raw[2 * e + 1]; sprev = e ? raw[2 * e - 2] : -1; }
    dst[e] = d;
    for (int r = sprev + 1; r <= s; ++r) row_start[r] = e;
    if (e == E_EDGES - 1)
        for (int r = s + 1; r <= N_NODES; ++r) row_start[r] = E_EDGES;
}

// ---------------------------------------------------------------------------
// K1b: W1 -> bf16 in MFMA B-fragment order.
// W1f[((s*16+t)*64+l)*8+j] = bf16(W1[k*D+n]), k = s*32+(l>>4)*8+j,
// n = t*16+(l&15). [B layout n=lane&15, k=quad*8+j — m89-verified]
// ---------------------------------------------------------------------------
__global__ __launch_bounds__(256) void wprep(const float* __restrict__ W1,
                                             bf16* __restrict__ W1f) {
    const int id = blockIdx.x * 256 + threadIdx.x;  // 65536 exact
    const int j = id & 7, l = (id >> 3) & 63, t = (id >> 9) & 15, s = id >> 13;
    const int k = s * 32 + (l >> 4) * 8 + j;
    const int n = t * 16 + (l & 15);
    W1f[id] = __float2bfloat16(W1[k * D + n]);
}

// ---------------------------------------------------------------------------
// K2: feats = X @ W1 + b1 via v_mfma_f32_16x16x32_bf16, fp32 accumulate.
// X read fp32 and converted to bf16 A-frags inline (xcast pass fused away).
// 625 blocks x 16 rows. Wave w owns cols 64w..64w+63. 32 MFMA/wave.
// Epilogue: +bias, bf16 feats store, fused a_src/a_dst row-dots.
// D layout: col=lane&15, row=quad*4+reg (m89/m91-verified).
// ---------------------------------------------------------------------------
__global__ __launch_bounds__(256) void gemm_mfma(const float* __restrict__ X,
                                                 const bf16* __restrict__ W1f,
                                                 const float* __restrict__ b1,
                                                 const float* __restrict__ Wa,
                                                 bf16* __restrict__ featsb,
                                                 float* __restrict__ a_src,
                                                 float* __restrict__ a_dst) {
    const int w = threadIdx.x >> 6, l = threadIdx.x & 63;
    const int quad = l >> 4, lan = l & 15;
    const int row0 = blockIdx.x * 16;

    floatx4 acc[4] = {{0.f, 0.f, 0.f, 0.f}, {0.f, 0.f, 0.f, 0.f},
                      {0.f, 0.f, 0.f, 0.f}, {0.f, 0.f, 0.f, 0.f}};

    // A-frags: lane reads X row (row0+lan) fp32, k = s*32+quad*8 .. +7
    const float4* Ax = (const float4*)(X + (size_t)(row0 + lan) * D);
    const short8* B8 = (const short8*)W1f;

    #pragma unroll
    for (int s = 0; s < 8; ++s) {
        const float4 u = Ax[s * 8 + quad * 2];
        const float4 v = Ax[s * 8 + quad * 2 + 1];
        short8 af;
        af[0] = (short)f2bu(u.x); af[1] = (short)f2bu(u.y);
        af[2] = (short)f2bu(u.z); af[3] = (short)f2bu(u.w);
        af[4] = (short)f2bu(v.x); af[5] = (short)f2bu(v.y);
        af[6] = (short)f2bu(v.z); af[7] = (short)f2bu(v.w);
        #pragma unroll
        for (int t = 0; t < 4; ++t) {
            const short8 bf = B8[(s * 16 + (4 * w + t)) * 64 + l];
            acc[t] = __builtin_amdgcn_mfma_f32_16x16x32_bf16(af, bf, acc[t], 0, 0, 0);
        }
    }

    // epilogue: lane l, tile t, reg r holds D[m][n], m=quad*4+r, n=(4w+t)*16+lan
    float p1[4] = {0.f, 0.f, 0.f, 0.f}, p2[4] = {0.f, 0.f, 0.f, 0.f};
    #pragma unroll
    for (int t = 0; t < 4; ++t) {
        const int n = (4 * w + t) * 16 + lan;
        const float bias = b1[n], wa1 = Wa[n], wa2 = Wa[D + n];
        #pragma unroll
        for (int r = 0; r < 4; ++r) {
            const float v = acc[t][r] + bias;
            featsb[(size_t)(row0 + quad * 4 + r) * D + n] = __float2bfloat16(v);
            p1[r] += v * wa1;
            p2[r] += v * wa2;
        }
    }

    // reduce across the 16 lanes of each quad (rows quad*4+r)
    __shared__ float red1[4][16], red2[4][16];
    #pragma unroll
    for (int r = 0; r < 4; ++r) {
        #pragma unroll
        for (int off = 1; off < 16; off <<= 1) {
            p1[r] += __shfl_xor(p1[r], off);
            p2[r] += __shfl_xor(p2[r], off);
        }
        if (lan == 0) { red1[w][quad * 4 + r] = p1[r]; red2[w][quad * 4 + r] = p2[r]; }
    }
    __syncthreads();
    if (threadIdx.x < 16) {
        const int m = threadIdx.x;
        a_src[row0 + m] = red1[0][m] + red1[1][m] + red1[2][m] + red1[3][m];
        a_dst[row0 + m] = red2[0][m] + red2[1][m] + red2[2][m] + red2[3][m];
    }
}

// ---------------------------------------------------------------------------
// K3: aggregate, one column-half per launch. One WAVE per node; lane l owns
// cols half*128 + 2l, 2l+1 (ushort2 = 4 B/lane, 256 B/wave-gather) from a
// 2.56 MB half-table — fits every XCD's 4 MB L2. Two sequential launches
// give temporal separation. dsum & scale wave-uniform (round-4 lesson).
// 8-deep edge unroll for MLP (8 outstanding gathers/wave).
// ---------------------------------------------------------------------------
__global__ __launch_bounds__(256) void aggregate_half(const int* __restrict__ dst,
                                                      const int* __restrict__ row_start,
                                                      const float* __restrict__ a_src,
                                                      const float* __restrict__ a_dst,
                                                      const float* __restrict__ ba,
                                                      const unsigned short* __restrict__ featsb,
                                                      float* __restrict__ out,
                                                      const int half) {
    const int i = blockIdx.x * 4 + (threadIdx.x >> 6);  // N_NODES % 4 == 0
    const int l = threadIdx.x & 63;
    const int rs = row_start[i], re = row_start[i + 1];
    const float base = a_src[i] + ba[0];
    const unsigned int* F = (const unsigned int*)featsb;  // row = 128 ushort2
    const int off = half * 64 + l;

    float2 acc = {0.f, 0.f};
    float dsum = 0.f;

    int e = rs;
    for (; e + 8 <= re; e += 8) {
        unsigned int fw[8];
        float xv[8];
        #pragma unroll
        for (int u = 0; u < 8; ++u) {
            const int d = dst[e + u];
            fw[u] = F[(size_t)d * 128 + off];
            float s = base + a_dst[d];
            s = (s > 0.f) ? s : LRELU_ALPHA * s;
            xv[u] = expf(s);
        }
        #pragma unroll
        for (int u = 0; u < 8; ++u) {
            acc.x += xv[u] * bu2f((unsigned short)(fw[u] & 0xffff));
            acc.y += xv[u] * bu2f((unsigned short)(fw[u] >> 16));
            dsum += xv[u];
        }
    }
    for (; e < re; ++e) {
        const int d = dst[e];
        const unsigned int f = F[(size_t)d * 128 + off];
        float s = base + a_dst[d];
        s = (s > 0.f) ? s : LRELU_ALPHA * s;
        const float x = expf(s);
        acc.x += x * bu2f((unsigned short)(f & 0xffff));
        acc.y += x * bu2f((unsigned short)(f >> 16));
        dsum += x;
    }

    const float inv = (re > rs) ? 1.f / dsum : 0.f;  // wave-uniform
    float2 o;
    o.x = acc.x * inv;
    o.y = acc.y * inv;
    ((float2*)out)[(size_t)i * 128 + off] = o;
}

// ---------------------------------------------------------------------------
extern "C" void kernel_launch(void* const* d_in, const int* in_sizes, int n_in,
                              void* d_out, int out_size, void* d_ws, size_t ws_size,
                              hipStream_t stream) {
    const float* X     = (const float*)d_in[0];
    const int*   edges = (const int*)d_in[1];
    const float* W1    = (const float*)d_in[2];
    const float* b1    = (const float*)d_in[3];
    const float* Wa    = (const float*)d_in[4];
    const float* ba    = (const float*)d_in[5];
    float* out = (float*)d_out;

    // workspace carve-up (~8 MB), all 16 B aligned
    bf16* featsb = (bf16*)d_ws;                            // N*D bf16 = 5.12 MB
    bf16* W1f    = featsb + (size_t)N_NODES * D;           // 64K bf16 = 128 KB
    float* a_src = (float*)(W1f + 65536);                  // N
    float* a_dst = a_src + N_NODES;                        // N
    int*   dstv  = (int*)(a_dst + N_NODES);                // E
    int*   row_start = dstv + E_EDGES;                     // N+1

    prep<<<(E_EDGES + 255) / 256, 256, 0, stream>>>(edges, dstv, row_start);
    wprep<<<65536 / 256, 256, 0, stream>>>(W1, W1f);
    gemm_mfma<<<N_NODES / 16, 256, 0, stream>>>(X, W1f, b1, Wa, featsb, a_src, a_dst);
    aggregate_half<<<N_NODES / 4, 256, 0, stream>>>(dstv, row_start, a_src, a_dst, ba,
                                                    (const unsigned short*)featsb, out, 0);
    aggregate_half<<<N_NODES / 4, 256, 0, stream>>>(dstv, row_start, a_src, a_dst, ba,
                                                    (const unsigned short*)featsb, out, 1);
}

// Round 10
// 108.694 us; speedup vs baseline: 1.1317x; 1.1317x over previous
//
#include <hip/hip_runtime.h>
#include <hip/hip_bf16.h>

#define N_NODES 10000
#define E_EDGES 320000
#define D 256
#define LRELU_ALPHA 0.2f

// fp32 world (round 3). dur_us includes ~56 us of harness re-poison fills
// (round-6 forensics). GEMM via mfma_f32_16x16x32_bf16 (round-8 win).
// Round-9 lesson: aggregate is bound by wave-serial per-edge overhead, not
// gather BW -> per-edge exp/score moved to the lane-parallel prep kernel,
// which now runs AFTER gemm (needs a_src/a_dst).

using short8  = __attribute__((ext_vector_type(8))) short;
using floatx4 = __attribute__((ext_vector_type(4))) float;
using bf16 = __hip_bfloat16;

__device__ __forceinline__ float bu2f(unsigned short u) {
    return __uint_as_float((unsigned)u << 16);
}
__device__ __forceinline__ unsigned short f2bu(float f) {
    union { bf16 b; unsigned short u; } cv;
    cv.b = __float2bfloat16(f);
    return cv.u;
}

// ---------------------------------------------------------------------------
// K1: W1 -> bf16 in MFMA B-fragment order.
// W1f[((s*16+t)*64+l)*8+j] = bf16(W1[k*D+n]), k = s*32+(l>>4)*8+j,
// n = t*16+(l&15). [B layout n=lane&15, k=quad*8+j — m89-verified]
// ---------------------------------------------------------------------------
__global__ __launch_bounds__(256) void wprep(const float* __restrict__ W1,
                                             bf16* __restrict__ W1f) {
    const int id = blockIdx.x * 256 + threadIdx.x;  // 65536 exact
    const int j = id & 7, l = (id >> 3) & 63, t = (id >> 9) & 15, s = id >> 13;
    const int k = s * 32 + (l >> 4) * 8 + j;
    const int n = t * 16 + (l & 15);
    W1f[id] = __float2bfloat16(W1[k * D + n]);
}

// ---------------------------------------------------------------------------
// K2: feats = X @ W1 + b1 via v_mfma_f32_16x16x32_bf16, fp32 accumulate.
// X read fp32 and converted to bf16 A-frags inline. 625 blocks x 16 rows.
// Wave w owns cols 64w..64w+63; 32 MFMA/wave. Epilogue: +bias, bf16 feats
// store, fused a_src/a_dst row-dots from fp32 accumulators.
// D layout: col=lane&15, row=quad*4+reg (m89/m91-verified).
// ---------------------------------------------------------------------------
__global__ __launch_bounds__(256) void gemm_mfma(const float* __restrict__ X,
                                                 const bf16* __restrict__ W1f,
                                                 const float* __restrict__ b1,
                                                 const float* __restrict__ Wa,
                                                 bf16* __restrict__ featsb,
                                                 float* __restrict__ a_src,
                                                 float* __restrict__ a_dst) {
    const int w = threadIdx.x >> 6, l = threadIdx.x & 63;
    const int quad = l >> 4, lan = l & 15;
    const int row0 = blockIdx.x * 16;

    floatx4 acc[4] = {{0.f, 0.f, 0.f, 0.f}, {0.f, 0.f, 0.f, 0.f},
                      {0.f, 0.f, 0.f, 0.f}, {0.f, 0.f, 0.f, 0.f}};

    const float4* Ax = (const float4*)(X + (size_t)(row0 + lan) * D);
    const short8* B8 = (const short8*)W1f;

    #pragma unroll
    for (int s = 0; s < 8; ++s) {
        const float4 u = Ax[s * 8 + quad * 2];
        const float4 v = Ax[s * 8 + quad * 2 + 1];
        short8 af;
        af[0] = (short)f2bu(u.x); af[1] = (short)f2bu(u.y);
        af[2] = (short)f2bu(u.z); af[3] = (short)f2bu(u.w);
        af[4] = (short)f2bu(v.x); af[5] = (short)f2bu(v.y);
        af[6] = (short)f2bu(v.z); af[7] = (short)f2bu(v.w);
        #pragma unroll
        for (int t = 0; t < 4; ++t) {
            const short8 bf = B8[(s * 16 + (4 * w + t)) * 64 + l];
            acc[t] = __builtin_amdgcn_mfma_f32_16x16x32_bf16(af, bf, acc[t], 0, 0, 0);
        }
    }

    float p1[4] = {0.f, 0.f, 0.f, 0.f}, p2[4] = {0.f, 0.f, 0.f, 0.f};
    #pragma unroll
    for (int t = 0; t < 4; ++t) {
        const int n = (4 * w + t) * 16 + lan;
        const float bias = b1[n], wa1 = Wa[n], wa2 = Wa[D + n];
        #pragma unroll
        for (int r = 0; r < 4; ++r) {
            const float v = acc[t][r] + bias;
            featsb[(size_t)(row0 + quad * 4 + r) * D + n] = __float2bfloat16(v);
            p1[r] += v * wa1;
            p2[r] += v * wa2;
        }
    }

    __shared__ float red1[4][16], red2[4][16];
    #pragma unroll
    for (int r = 0; r < 4; ++r) {
        #pragma unroll
        for (int off = 1; off < 16; off <<= 1) {
            p1[r] += __shfl_xor(p1[r], off);
            p2[r] += __shfl_xor(p2[r], off);
        }
        if (lan == 0) { red1[w][quad * 4 + r] = p1[r]; red2[w][quad * 4 + r] = p2[r]; }
    }
    __syncthreads();
    if (threadIdx.x < 16) {
        const int m = threadIdx.x;
        a_src[row0 + m] = red1[0][m] + red1[1][m] + red1[2][m] + red1[3][m];
        a_dst[row0 + m] = red2[0][m] + red2[1][m] + red2[2][m] + red2[3][m];
    }
}

// ---------------------------------------------------------------------------
// K3: edges -> CSR row_start + packed per-edge (dst, exp(lrelu(score))).
// One edge per THREAD: score math is lane-parallel here (64 edges per
// wave-instruction) instead of wave-serial in the aggregate loop (round-9
// lesson). src is sorted -> a_src[s] coalesced; a_dst is 40 KB (L1/L2).
// ---------------------------------------------------------------------------
__global__ __launch_bounds__(256) void prep(const int* __restrict__ raw,
                                            const float* __restrict__ a_src,
                                            const float* __restrict__ a_dst,
                                            const float* __restrict__ ba,
                                            int2* __restrict__ edata,
                                            int* __restrict__ row_start) {
    bool is64 = true;  // int64 rows: [s_lo, s_hi, d_lo, d_hi], hi words == 0
    #pragma unroll
    for (int t = 0; t < 16; ++t)
        if (raw[2 * t + 1] != 0) is64 = false;

    int e = blockIdx.x * 256 + threadIdx.x;
    if (e >= E_EDGES) return;
    int s, d, sprev;
    if (is64) { s = raw[4 * e]; d = raw[4 * e + 2]; sprev = e ? raw[4 * e - 4] : -1; }
    else      { s = raw[2 * e]; d = raw[2 * e + 1]; sprev = e ? raw[2 * e - 2] : -1; }

    float sc = a_src[s] + a_dst[d] + ba[0];
    sc = (sc > 0.f) ? sc : LRELU_ALPHA * sc;
    edata[e] = make_int2(d, __float_as_int(expf(sc)));

    for (int r = sprev + 1; r <= s; ++r) row_start[r] = e;
    if (e == E_EDGES - 1)
        for (int r = s + 1; r <= N_NODES; ++r) row_start[r] = E_EDGES;
}

// ---------------------------------------------------------------------------
// K4: out[i,:] = (sum_e ex[e] * feats[dst[e],:]) / sum_e ex[e].
// One WAVE per node; lane l owns cols 4l..4l+3 (ushort4 bf16, 8 B/lane,
// 512 B/wave-gather). Per edge: one 8 B wave-uniform edata load + one
// gather + 4 cvt-fma + dsum add (~12 wave-instr). dsum & scale are
// wave-uniform (round-4 lesson): no reduce, no LDS, no syncthreads.
// ---------------------------------------------------------------------------
__global__ __launch_bounds__(256) void aggregate(const int2* __restrict__ edata,
                                                 const int* __restrict__ row_start,
                                                 const unsigned short* __restrict__ featsb,
                                                 float* __restrict__ out) {
    const int i = blockIdx.x * 4 + (threadIdx.x >> 6);  // N_NODES % 4 == 0
    const int l = threadIdx.x & 63;
    const int rs = row_start[i], re = row_start[i + 1];
    const ushort4* F = (const ushort4*)featsb;

    float4 acc = {0.f, 0.f, 0.f, 0.f};
    float dsum = 0.f;

    int e = rs;
    for (; e + 8 <= re; e += 8) {  // 8 independent gathers in flight
        int2 ed[8];
        #pragma unroll
        for (int u = 0; u < 8; ++u) ed[u] = edata[e + u];
        #pragma unroll
        for (int u = 0; u < 8; ++u) {
            const ushort4 f = F[(size_t)ed[u].x * 64 + l];
            const float x = __int_as_float(ed[u].y);
            acc.x += x * bu2f(f.x); acc.y += x * bu2f(f.y);
            acc.z += x * bu2f(f.z); acc.w += x * bu2f(f.w);
            dsum += x;
        }
    }
    for (; e < re; ++e) {
        const int2 ed = edata[e];
        const ushort4 f = F[(size_t)ed.x * 64 + l];
        const float x = __int_as_float(ed.y);
        acc.x += x * bu2f(f.x); acc.y += x * bu2f(f.y);
        acc.z += x * bu2f(f.z); acc.w += x * bu2f(f.w);
        dsum += x;
    }

    const float inv = (re > rs) ? 1.f / dsum : 0.f;  // wave-uniform
    float4 o;
    o.x = acc.x * inv; o.y = acc.y * inv; o.z = acc.z * inv; o.w = acc.w * inv;
    ((float4*)out)[(size_t)i * 64 + l] = o;
}

// ---------------------------------------------------------------------------
extern "C" void kernel_launch(void* const* d_in, const int* in_sizes, int n_in,
                              void* d_out, int out_size, void* d_ws, size_t ws_size,
                              hipStream_t stream) {
    const float* X     = (const float*)d_in[0];
    const int*   edges = (const int*)d_in[1];
    const float* W1    = (const float*)d_in[2];
    const float* b1    = (const float*)d_in[3];
    const float* Wa    = (const float*)d_in[4];
    const float* ba    = (const float*)d_in[5];
    float* out = (float*)d_out;

    // workspace carve-up (~8.5 MB), all 16 B aligned
    bf16* featsb = (bf16*)d_ws;                            // N*D bf16 = 5.12 MB
    bf16* W1f    = featsb + (size_t)N_NODES * D;           // 64K bf16 = 128 KB
    float* a_src = (float*)(W1f + 65536);                  // N
    float* a_dst = a_src + N_NODES;                        // N
    int2*  edata = (int2*)(a_dst + N_NODES);               // E int2 = 2.56 MB
    int*   row_start = (int*)(edata + E_EDGES);            // N+1

    wprep<<<65536 / 256, 256, 0, stream>>>(W1, W1f);
    gemm_mfma<<<N_NODES / 16, 256, 0, stream>>>(X, W1f, b1, Wa, featsb, a_src, a_dst);
    prep<<<(E_EDGES + 255) / 256, 256, 0, stream>>>(edges, a_src, a_dst, ba, edata, row_start);
    aggregate<<<N_NODES / 4, 256, 0, stream>>>(edata, row_start,
                                               (const unsigned short*)featsb, out);
}

// Round 11
// 102.750 us; speedup vs baseline: 1.1971x; 1.0578x over previous
//
#include <hip/hip_runtime.h>
#include <hip/hip_bf16.h>

#define N_NODES 10000
#define E_EDGES 320000
#define D 256
#define LRELU_ALPHA 0.2f

// fp32 world (round 3). dur_us includes ~56 us of harness re-poison fills
// (round-6 forensics). GEMM via mfma_f32_16x16x32_bf16 (round-8 win).
// Per-edge exp/score lane-parallel in prep (round-10 win). Round 11:
// aggregate stages edata through wave-private LDS — 1 coalesced vmem per
// ~32 edges instead of one uniform vmem per edge.

using short8  = __attribute__((ext_vector_type(8))) short;
using floatx4 = __attribute__((ext_vector_type(4))) float;
using bf16 = __hip_bfloat16;

__device__ __forceinline__ float bu2f(unsigned short u) {
    return __uint_as_float((unsigned)u << 16);
}
__device__ __forceinline__ unsigned short f2bu(float f) {
    union { bf16 b; unsigned short u; } cv;
    cv.b = __float2bfloat16(f);
    return cv.u;
}

// ---------------------------------------------------------------------------
// K1: W1 -> bf16 in MFMA B-fragment order.
// W1f[((s*16+t)*64+l)*8+j] = bf16(W1[k*D+n]), k = s*32+(l>>4)*8+j,
// n = t*16+(l&15). [B layout n=lane&15, k=quad*8+j — m89-verified]
// ---------------------------------------------------------------------------
__global__ __launch_bounds__(256) void wprep(const float* __restrict__ W1,
                                             bf16* __restrict__ W1f) {
    const int id = blockIdx.x * 256 + threadIdx.x;  // 65536 exact
    const int j = id & 7, l = (id >> 3) & 63, t = (id >> 9) & 15, s = id >> 13;
    const int k = s * 32 + (l >> 4) * 8 + j;
    const int n = t * 16 + (l & 15);
    W1f[id] = __float2bfloat16(W1[k * D + n]);
}

// ---------------------------------------------------------------------------
// K2: feats = X @ W1 + b1 via v_mfma_f32_16x16x32_bf16, fp32 accumulate.
// X read fp32 and converted to bf16 A-frags inline. 625 blocks x 16 rows.
// Wave w owns cols 64w..64w+63; 32 MFMA/wave. Epilogue: +bias, bf16 feats
// store, fused a_src/a_dst row-dots from fp32 accumulators.
// D layout: col=lane&15, row=quad*4+reg (m89/m91-verified).
// ---------------------------------------------------------------------------
__global__ __launch_bounds__(256) void gemm_mfma(const float* __restrict__ X,
                                                 const bf16* __restrict__ W1f,
                                                 const float* __restrict__ b1,
                                                 const float* __restrict__ Wa,
                                                 bf16* __restrict__ featsb,
                                                 float* __restrict__ a_src,
                                                 float* __restrict__ a_dst) {
    const int w = threadIdx.x >> 6, l = threadIdx.x & 63;
    const int quad = l >> 4, lan = l & 15;
    const int row0 = blockIdx.x * 16;

    floatx4 acc[4] = {{0.f, 0.f, 0.f, 0.f}, {0.f, 0.f, 0.f, 0.f},
                      {0.f, 0.f, 0.f, 0.f}, {0.f, 0.f, 0.f, 0.f}};

    const float4* Ax = (const float4*)(X + (size_t)(row0 + lan) * D);
    const short8* B8 = (const short8*)W1f;

    #pragma unroll
    for (int s = 0; s < 8; ++s) {
        const float4 u = Ax[s * 8 + quad * 2];
        const float4 v = Ax[s * 8 + quad * 2 + 1];
        short8 af;
        af[0] = (short)f2bu(u.x); af[1] = (short)f2bu(u.y);
        af[2] = (short)f2bu(u.z); af[3] = (short)f2bu(u.w);
        af[4] = (short)f2bu(v.x); af[5] = (short)f2bu(v.y);
        af[6] = (short)f2bu(v.z); af[7] = (short)f2bu(v.w);
        #pragma unroll
        for (int t = 0; t < 4; ++t) {
            const short8 bf = B8[(s * 16 + (4 * w + t)) * 64 + l];
            acc[t] = __builtin_amdgcn_mfma_f32_16x16x32_bf16(af, bf, acc[t], 0, 0, 0);
        }
    }

    float p1[4] = {0.f, 0.f, 0.f, 0.f}, p2[4] = {0.f, 0.f, 0.f, 0.f};
    #pragma unroll
    for (int t = 0; t < 4; ++t) {
        const int n = (4 * w + t) * 16 + lan;
        const float bias = b1[n], wa1 = Wa[n], wa2 = Wa[D + n];
        #pragma unroll
        for (int r = 0; r < 4; ++r) {
            const float v = acc[t][r] + bias;
            featsb[(size_t)(row0 + quad * 4 + r) * D + n] = __float2bfloat16(v);
            p1[r] += v * wa1;
            p2[r] += v * wa2;
        }
    }

    __shared__ float red1[4][16], red2[4][16];
    #pragma unroll
    for (int r = 0; r < 4; ++r) {
        #pragma unroll
        for (int off = 1; off < 16; off <<= 1) {
            p1[r] += __shfl_xor(p1[r], off);
            p2[r] += __shfl_xor(p2[r], off);
        }
        if (lan == 0) { red1[w][quad * 4 + r] = p1[r]; red2[w][quad * 4 + r] = p2[r]; }
    }
    __syncthreads();
    if (threadIdx.x < 16) {
        const int m = threadIdx.x;
        a_src[row0 + m] = red1[0][m] + red1[1][m] + red1[2][m] + red1[3][m];
        a_dst[row0 + m] = red2[0][m] + red2[1][m] + red2[2][m] + red2[3][m];
    }
}

// ---------------------------------------------------------------------------
// K3: edges -> CSR row_start + packed per-edge (dst_byte_offset, exp(lrelu)).
// One edge per THREAD (lane-parallel score math — round-10 win). dst is
// pre-scaled to the feats-row byte offset (d*512) to shorten the aggregate
// address path. src sorted -> a_src[s] coalesced; a_dst 40 KB (L1/L2).
// ---------------------------------------------------------------------------
__global__ __launch_bounds__(256) void prep(const int* __restrict__ raw,
                                            const float* __restrict__ a_src,
                                            const float* __restrict__ a_dst,
                                            const float* __restrict__ ba,
                                            int2* __restrict__ edata,
                                            int* __restrict__ row_start) {
    bool is64 = true;  // int64 rows: [s_lo, s_hi, d_lo, d_hi], hi words == 0
    #pragma unroll
    for (int t = 0; t < 16; ++t)
        if (raw[2 * t + 1] != 0) is64 = false;

    int e = blockIdx.x * 256 + threadIdx.x;
    if (e >= E_EDGES) return;
    int s, d, sprev;
    if (is64) { s = raw[4 * e]; d = raw[4 * e + 2]; sprev = e ? raw[4 * e - 4] : -1; }
    else      { s = raw[2 * e]; d = raw[2 * e + 1]; sprev = e ? raw[2 * e - 2] : -1; }

    float sc = a_src[s] + a_dst[d] + ba[0];
    sc = (sc > 0.f) ? sc : LRELU_ALPHA * sc;
    edata[e] = make_int2(d << 9, __float_as_int(expf(sc)));  // d*512 byte offset

    for (int r = sprev + 1; r <= s; ++r) row_start[r] = e;
    if (e == E_EDGES - 1)
        for (int r = s + 1; r <= N_NODES; ++r) row_start[r] = E_EDGES;
}

// ---------------------------------------------------------------------------
// K4: out[i,:] = (sum_e ex[e] * feats[dst[e],:]) / sum_e ex[e].
// One WAVE per node; lane l owns cols 4l..4l+3 (ushort4 bf16, 512 B/wave
// gather). Edge metadata staged through wave-private LDS: ONE coalesced
// 512 B load covers up to 64 edges (avg degree 32 -> typically one load
// per node), replacing per-edge wave-uniform vmem loads. Same-wave LDS is
// in-order -> no __syncthreads (different waves iterate independently).
// dsum & scale wave-uniform (round-4 lesson). Edge order ascending ->
// bit-identical sums vs round 10.
// ---------------------------------------------------------------------------
__global__ __launch_bounds__(256) void aggregate(const int2* __restrict__ edata,
                                                 const int* __restrict__ row_start,
                                                 const unsigned short* __restrict__ featsb,
                                                 float* __restrict__ out) {
    __shared__ int2 els[4][64];
    const int wv = threadIdx.x >> 6, l = threadIdx.x & 63;
    const int i = blockIdx.x * 4 + wv;  // N_NODES % 4 == 0
    const int rs = row_start[i], re = row_start[i + 1];
    const char* Fb = (const char*)featsb;

    float4 acc = {0.f, 0.f, 0.f, 0.f};
    float dsum = 0.f;

    for (int e = rs; e < re; e += 64) {
        const int cnt = min(64, re - e);
        if (l < cnt) els[wv][l] = edata[e + l];
        __builtin_amdgcn_wave_barrier();  // keep write before reads in sched

        int j = 0;
        for (; j + 8 <= cnt; j += 8) {
            #pragma unroll
            for (int u = 0; u < 8; ++u) {
                const int2 ed = els[wv][j + u];
                const ushort4 f = *(const ushort4*)(Fb + (size_t)(unsigned)ed.x + l * 8);
                const float x = __int_as_float(ed.y);
                acc.x += x * bu2f(f.x); acc.y += x * bu2f(f.y);
                acc.z += x * bu2f(f.z); acc.w += x * bu2f(f.w);
                dsum += x;
            }
        }
        for (; j < cnt; ++j) {
            const int2 ed = els[wv][j];
            const ushort4 f = *(const ushort4*)(Fb + (size_t)(unsigned)ed.x + l * 8);
            const float x = __int_as_float(ed.y);
            acc.x += x * bu2f(f.x); acc.y += x * bu2f(f.y);
            acc.z += x * bu2f(f.z); acc.w += x * bu2f(f.w);
            dsum += x;
        }
        __builtin_amdgcn_wave_barrier();  // next batch's write after reads
    }

    const float inv = (re > rs) ? 1.f / dsum : 0.f;  // wave-uniform
    float4 o;
    o.x = acc.x * inv; o.y = acc.y * inv; o.z = acc.z * inv; o.w = acc.w * inv;
    ((float4*)out)[(size_t)i * 64 + l] = o;
}

// ---------------------------------------------------------------------------
extern "C" void kernel_launch(void* const* d_in, const int* in_sizes, int n_in,
                              void* d_out, int out_size, void* d_ws, size_t ws_size,
                              hipStream_t stream) {
    const float* X     = (const float*)d_in[0];
    const int*   edges = (const int*)d_in[1];
    const float* W1    = (const float*)d_in[2];
    const float* b1    = (const float*)d_in[3];
    const float* Wa    = (const float*)d_in[4];
    const float* ba    = (const float*)d_in[5];
    float* out = (float*)d_out;

    // workspace carve-up (~8.5 MB), all 16 B aligned
    bf16* featsb = (bf16*)d_ws;                            // N*D bf16 = 5.12 MB
    bf16* W1f    = featsb + (size_t)N_NODES * D;           // 64K bf16 = 128 KB
    float* a_src = (float*)(W1f + 65536);                  // N
    float* a_dst = a_src + N_NODES;                        // N
    int2*  edata = (int2*)(a_dst + N_NODES);               // E int2 = 2.56 MB
    int*   row_start = (int*)(edata + E_EDGES);            // N+1

    wprep<<<65536 / 256, 256, 0, stream>>>(W1, W1f);
    gemm_mfma<<<N_NODES / 16, 256, 0, stream>>>(X, W1f, b1, Wa, featsb, a_src, a_dst);
    prep<<<(E_EDGES + 255) / 256, 256, 0, stream>>>(edges, a_src, a_dst, ba, edata, row_start);
    aggregate<<<N_NODES / 4, 256, 0, stream>>>(edata, row_start,
                                               (const unsigned short*)featsb, out);
}